// Round 8
// baseline (83557.538 us; speedup 1.0000x reference)
//
#include <hip/hip_runtime.h>
#include <cstdint>

#define DEV static __device__ __forceinline__

DEV float gelu_f(float x){
    float x3 = x*x*x;
    return 0.5f*x*(1.f + tanhf(0.7978845608f*(x + 0.044715f*x3)));
}

// ---------------- naive fp32 GEMM: C[M][N] (mode) A[M][K] @ W[K][N] ----------------
// MODE 0: C = v                MODE 1: C += v
// MODE 2: C = gelu(v + bias[n])           (MoE up)
// MODE 3: C += (v + bias[n]) * rowscale[m] (MoE down, weighted accumulate)
template<int MODE>
__global__ __launch_bounds__(256) void ngemm(
    const float* __restrict__ A, const float* __restrict__ W, float* __restrict__ C,
    const float* __restrict__ bias, const float* __restrict__ rowscale,
    int M, int N, int K, int ldc){
    __shared__ float As[16][17];
    __shared__ float Ws[16][17];
    int tx = threadIdx.x, ty = threadIdx.y;
    int n = blockIdx.x*16 + tx;
    int m = blockIdx.y*16 + ty;
    float acc = 0.f;
    for (int k0 = 0; k0 < K; k0 += 16){
        As[ty][tx] = A[(size_t)m*K + k0 + tx];
        Ws[ty][tx] = W[(size_t)(k0+ty)*N + n];
        __syncthreads();
        #pragma unroll
        for (int kk = 0; kk < 16; ++kk) acc += As[ty][kk]*Ws[kk][tx];
        __syncthreads();
    }
    size_t o = (size_t)m*ldc + n;
    if (MODE == 0)      C[o] = acc;
    else if (MODE == 1) C[o] += acc;
    else if (MODE == 2) C[o] = gelu_f(acc + bias[n]);
    else if (MODE == 3) C[o] += (acc + bias[n])*rowscale[m];
}

// ---------------- qk-norm in place on fp32 qkv [4096][3072] ----------------
__global__ __launch_bounds__(256) void qknorm_ip(
    float* __restrict__ qkvf, const float* __restrict__ qs, const float* __restrict__ ks){
    int t = blockIdx.x*4 + (threadIdx.x>>6);
    int lane = threadIdx.x & 63;
    int h = lane>>2, d0 = (lane&3)*16;
    float* qp = qkvf + (size_t)t*3072 + h*64 + d0;
    float* kp = qp + 1024;
    float qv[16], kv[16];
    float sq = 0.f, sk = 0.f;
    #pragma unroll
    for (int i=0;i<16;++i){
        qv[i] = qp[i]; kv[i] = kp[i];
        sq += qv[i]*qv[i];  sk += kv[i]*kv[i];
    }
    sq += __shfl_xor(sq,1); sq += __shfl_xor(sq,2);
    sk += __shfl_xor(sk,1); sk += __shfl_xor(sk,2);
    float rq = rsqrtf(sq + 1e-6f) * 10.f;
    float rk = rsqrtf(sk + 1e-6f);
    #pragma unroll
    for (int i=0;i<16;++i){
        qp[i] = qv[i]*rq*qs[d0+i];
        kp[i] = kv[i]*rk*ks[d0+i];
    }
}

// ---------------- gating: logits = h @ Wg, top-2 softmax -> dense wE[8][4096] ----------------
__global__ __launch_bounds__(256) void gating_kernel(
    const float* __restrict__ h, const float* __restrict__ Wg,
    float* __restrict__ wE){
    int t = blockIdx.x*4 + (threadIdx.x>>6);
    int lane = threadIdx.x & 63;
    const float* xr = h + (size_t)t*1024;
    float s[8] = {0,0,0,0,0,0,0,0};
    #pragma unroll
    for (int i=0;i<16;++i){
        int d = lane*16 + i;
        float xv = xr[d];
        const float* wr = Wg + d*8;
        #pragma unroll
        for (int ee=0;ee<8;++ee) s[ee] += xv * wr[ee];
    }
    #pragma unroll
    for (int off=1;off<64;off<<=1){
        #pragma unroll
        for (int ee=0;ee<8;++ee) s[ee] += __shfl_xor(s[ee], off);
    }
    if (lane == 0){
        int b0 = 0; float v0 = s[0];
        #pragma unroll
        for (int ee=1;ee<8;++ee) if (s[ee] > v0){ v0 = s[ee]; b0 = ee; }
        int b1i = -1; float v1 = -3e38f;
        #pragma unroll
        for (int ee=0;ee<8;++ee) if (ee != b0 && s[ee] > v1){ v1 = s[ee]; b1i = ee; }
        float z = __expf(v1 - v0);
        float inv = 1.f/(1.f + z);
        #pragma unroll
        for (int ee=0;ee<8;++ee) wE[ee*4096 + t] = 0.f;
        wE[b0*4096 + t]  = inv;
        wE[b1i*4096 + t] = z*inv;
    }
}

// ---------------- naive fp32 attention, one wave per (query i, bh) ----------------
__global__ __launch_bounds__(64) void attn_naive(
    const float* __restrict__ qkvf, float* __restrict__ af){
    int i = blockIdx.x, bh = blockIdx.y;
    int b = bh>>4, h = bh&15;
    int lane = threadIdx.x;
    __shared__ float qv[64];
    __shared__ float accs[64][65];
    qv[lane] = qkvf[(size_t)(b*2048 + i)*3072 + h*64 + lane];
    __syncthreads();
    float lmax = -3e38f;
    for (int j = lane; j <= i; j += 64){
        const float* kp = qkvf + (size_t)(b*2048 + j)*3072 + 1024 + h*64;
        float s = 0.f;
        #pragma unroll
        for (int d=0; d<64; ++d) s += qv[d]*kp[d];
        lmax = fmaxf(lmax, s);
    }
    #pragma unroll
    for (int off=1; off<64; off<<=1) lmax = fmaxf(lmax, __shfl_xor(lmax, off));
    float acc[64];
    #pragma unroll
    for (int d=0; d<64; ++d) acc[d] = 0.f;
    float lsum = 0.f;
    for (int j = lane; j <= i; j += 64){
        const float* kp = qkvf + (size_t)(b*2048 + j)*3072 + 1024 + h*64;
        float s = 0.f;
        #pragma unroll
        for (int d=0; d<64; ++d) s += qv[d]*kp[d];
        float p = __expf(s - lmax);
        lsum += p;
        const float* vp = qkvf + (size_t)(b*2048 + j)*3072 + 2048 + h*64;
        #pragma unroll
        for (int d=0; d<64; ++d) acc[d] += p * vp[d];
    }
    #pragma unroll
    for (int off=1; off<64; off<<=1) lsum += __shfl_xor(lsum, off);
    #pragma unroll
    for (int d=0; d<64; ++d) accs[lane][d] = acc[d];
    __syncthreads();
    float tot = 0.f;
    for (int l2=0; l2<64; ++l2) tot += accs[l2][lane];
    af[(size_t)(b*2048 + i)*1024 + h*64 + lane] = tot/lsum;
}

// ---------------- launcher ----------------
extern "C" void kernel_launch(void* const* d_in, const int* in_sizes, int n_in,
                              void* d_out, int out_size, void* d_ws, size_t ws_size,
                              hipStream_t stream){
    const float* x  = (const float*)d_in[0];
    const float* Wq = (const float*)d_in[1];
    const float* Wk = (const float*)d_in[2];
    const float* Wv = (const float*)d_in[3];
    const float* Wo = (const float*)d_in[4];
    const float* qs = (const float*)d_in[5];
    const float* ks = (const float*)d_in[6];
    const float* Wg = (const float*)d_in[7];
    const float* W1 = (const float*)d_in[8];
    const float* b1 = (const float*)d_in[9];
    const float* W2 = (const float*)d_in[10];
    const float* b2 = (const float*)d_in[11];

    char* base = (char*)d_ws;
    const size_t MB = 1024*1024;
    float* qkvf  = (float*)base;               // [4096][3072] fp32, 48 MB
    float* af    = (float*)(base + 48*MB);     // [4096][1024] fp32, 16 MB (attn out)
    float* hsave = (float*)(base + 64*MB);     // [4096][1024] fp32, 16 MB (layer input snapshot)
    float* Hc    = (float*)(base + 80*MB);     // [1024][4096] fp32, 16 MB (MoE hidden chunk)
    float* wE    = (float*)(base + 96*MB);     // [8][4096] fp32

    float* hf = (float*)d_out;   // fp32 hidden state, accumulated in place
    const size_t HTOK = (size_t)4096*1024;
    hipMemcpyAsync(hf, x, HTOK*4, hipMemcpyDeviceToDevice, stream);

    const dim3 blk(16,16);
    for (int l=0; l<2; ++l){
        const size_t WSTRIDE = (size_t)1024*1024;
        const size_t ESTRIDE = (size_t)1024*4096;

        // snapshot layer input h (the MoE and nothing else reads it after hf is updated)
        hipMemcpyAsync(hsave, hf, HTOK*4, hipMemcpyDeviceToDevice, stream);

        gating_kernel<<<1024,256,0,stream>>>(hf, Wg + (size_t)l*1024*8, wE);

        // QKV: qkvf[:,0:1024]=h@Wq, [:,1024:2048]=h@Wk, [:,2048:3072]=h@Wv
        ngemm<0><<<dim3(64,256),blk,0,stream>>>(hf, Wq + l*WSTRIDE, qkvf,        nullptr,nullptr, 4096,1024,1024,3072);
        ngemm<0><<<dim3(64,256),blk,0,stream>>>(hf, Wk + l*WSTRIDE, qkvf + 1024, nullptr,nullptr, 4096,1024,1024,3072);
        ngemm<0><<<dim3(64,256),blk,0,stream>>>(hf, Wv + l*WSTRIDE, qkvf + 2048, nullptr,nullptr, 4096,1024,1024,3072);

        qknorm_ip<<<1024,256,0,stream>>>(qkvf, qs + l*64, ks + l*64);
        attn_naive<<<dim3(2048,32),64,0,stream>>>(qkvf, af);

        // residual: hf += attn_out @ Wo   (hf becomes h + attn)
        ngemm<1><<<dim3(64,256),blk,0,stream>>>(af, Wo + l*WSTRIDE, hf, nullptr,nullptr, 4096,1024,1024,1024);

        // dense all-experts MoE on the ORIGINAL layer input hsave, chunked over tokens
        for (int e=0; e<8; ++e){
            const float* W1e = W1 + ((size_t)l*8 + e)*ESTRIDE;
            const float* W2e = W2 + ((size_t)l*8 + e)*ESTRIDE;
            const float* b1e = b1 + ((size_t)l*8 + e)*4096;
            const float* b2e = b2 + ((size_t)l*8 + e)*1024;
            for (int c=0; c<4; ++c){
                const float* Ac = hsave + (size_t)c*1024*1024;
                ngemm<2><<<dim3(256,64),blk,0,stream>>>(Ac, W1e, Hc, b1e, nullptr, 1024,4096,1024,4096);
                ngemm<3><<<dim3(64,64),blk,0,stream>>>(Hc, W2e, hf + (size_t)c*1024*1024,
                                                       b2e, wE + e*4096 + c*1024, 1024,1024,4096,1024);
            }
        }
    }
}